// Round 11
// baseline (1340.468 us; speedup 1.0000x reference)
//
#include <hip/hip_runtime.h>
#include <math.h>

#define B 16
#define CH 128
#define DIM 128
#define MODES 32
#define NLAYERS 4
#define PROJ 128
#define U 64            // stored kx modes: u<32 -> kx=u ; u>=32 -> kx=u+64 (96..127)
#define KY 32
#define NMODE (U*KY)    // 2048
#define N2 (DIM*DIM)    // 16384
#define PG 32           // p-groups in idft
#define PPG (PROJ/PG)   // 4 p per group

__device__ __forceinline__ void async16(const void* g, void* l) {
  __builtin_amdgcn_global_load_lds((const __attribute__((address_space(1))) unsigned int*)g,
                                   (__attribute__((address_space(3))) unsigned int*)l, 16, 0, 0);
}

// ---------------- K1a: t1[b][x][ky] = sum_y z[b][x][y] e^{-2pi i ky y/128} ----------------
__global__ __launch_bounds__(256) void k_zf1(const float* __restrict__ z,
                                             float2* __restrict__ t1) {
  __shared__ float zrow[16][DIM];
  __shared__ float2 tw[DIM];
  int bid = blockIdx.x;
  int b = bid >> 3, xt = bid & 7;
  int x0 = xt * 16;
  int t = threadIdx.x;
  if (t < 128) {
    float ang = (float)(2.0 * M_PI) * (float)t / 128.0f;
    tw[t] = make_float2(cosf(ang), sinf(ang));
  }
  for (int e = t; e < 16 * DIM / 4; e += 256)
    ((float4*)&zrow[0][0])[e] = ((const float4*)&z[b * N2 + x0 * DIM])[e];
  __syncthreads();
  #pragma unroll
  for (int j = 0; j < 2; ++j) {
    int it = t + j * 256;
    int x_l = it >> 5, ky = it & 31;
    float tr = 0.f, ti = 0.f;
    for (int y = 0; y < DIM; ++y) {
      float v = zrow[x_l][y];
      float2 w = tw[(ky * y) & 127];
      tr += v * w.x;
      ti -= v * w.y;
    }
    t1[((size_t)b * DIM + x0 + x_l) * KY + ky] = make_float2(tr, ti);
  }
}

// ---------------- K1b: zf[b][u][ky] = sum_x t1[b][x][ky] e^{-2pi i kx x/128} ----------------
__global__ __launch_bounds__(256) void k_zf2(const float2* __restrict__ t1,
                                             float* __restrict__ zfr, float* __restrict__ zfi) {
  __shared__ float2 t1s[DIM][KY];
  __shared__ float2 tw[DIM];
  int bid = blockIdx.x;
  int b = bid >> 1, uh = bid & 1;
  int t = threadIdx.x;
  if (t < 128) {
    float ang = (float)(2.0 * M_PI) * (float)t / 128.0f;
    tw[t] = make_float2(cosf(ang), sinf(ang));
  }
  for (int e = t; e < DIM * KY / 2; e += 256)
    ((float4*)&t1s[0][0])[e] = ((const float4*)&t1[(size_t)b * DIM * KY])[e];
  __syncthreads();
  #pragma unroll
  for (int j = 0; j < 4; ++j) {
    int m = t + j * 256;
    int u_l = m >> 5, ky = m & 31;
    int u = uh * 32 + u_l;
    int kx = (u < 32) ? u : (u + 64);
    float ar = 0.f, ai = 0.f;
    for (int x = 0; x < DIM; ++x) {
      float2 v = t1s[x][ky];
      float2 w = tw[(kx * x) & 127];
      ar += v.x * w.x + v.y * w.y;
      ai += v.y * w.x - v.x * w.y;
    }
    zfr[b * NMODE + u * KY + ky] = ar;
    zfi[b * NMODE + u * KY + ky] = ai;
  }
}

// ---------------- K2: lift in spectral space (float2 out) ----------------
__global__ __launch_bounds__(256) void k_lift(const float* __restrict__ zfr, const float* __restrict__ zfi,
                                              const float* __restrict__ lw, const float* __restrict__ lb,
                                              float2* __restrict__ vcout) {
  int idx = blockIdx.x * 256 + threadIdx.x;
  if (idx >= B * CH * NMODE) return;
  int m = idx & (NMODE - 1);
  int c = (idx >> 11) & 127;
  int b = idx >> 18;
  float w = lw[c];
  float re = w * zfr[b * NMODE + m];
  float im = w * zfi[b * NMODE + m];
  if (m == 0) re += 16384.f * lb[c];
  vcout[idx] = make_float2(re, im);
}

// ---------------- K3: spectral einsum, one layer ----------------
// grid = 1024: g = bid&7 = u-octet (u = g*8..g*8+7) pinned to one XCD;
// r = bid>>3: ot = r&31 (o-tile of 4), bq = r>>5 (b-quarter of 4).
// KEY: per (i,o) the block reads kxw0..kxw0+7 x ky -> 1 KB CONTIGUOUS per async16
// (previous variants read 128B @ 4KB stride -> DRAM-inefficient; the ~140us/layer wall).
// chunk = 1 i = 16 KB (8 W units + 8 V units of 1 KB); ring of 4; counted vmcnt
// (every wave issues exactly 4 async16/chunk).
__global__ __launch_bounds__(256) void k_spec(const float2* __restrict__ vc,
                                              const float* __restrict__ wr1, const float* __restrict__ wi1,
                                              const float* __restrict__ wr2, const float* __restrict__ wi2,
                                              float2* __restrict__ oc) {
  __shared__ float4 ring[4][1024];          // 4 bufs x 16 KB: [W 8KB | V 8KB]
  int bid = blockIdx.x;
  int g = bid & 7;
  int r = bid >> 3;
  int ot = r & 31, bq = r >> 5;
  int o0 = ot * 4, b0 = bq * 4;
  int u0 = g * 8;
  int kxw0 = (g & 3) * 8;
  const float* wr = (g >= 4) ? wr2 : wr1;
  const float* wi = (g >= 4) ? wi2 : wi1;
  int t = threadIdx.x;
  int u_l = t >> 5, ky = t & 31;
  int wv = t >> 6, lane = t & 63;
  float accR[4][4] = {}, accI[4][4] = {};

  #define STAGE(c)                                                                   \
    if ((c) < 128) {                                                                 \
      char* dst0 = (char*)&ring[(c) & 3][0];                                         \
      _Pragma("unroll")                                                              \
      for (int n = 0; n < 4; ++n) {                                                  \
        int nu = wv * 4 + n;                                                         \
        if (nu < 8) {                                                                \
          int o_l = nu >> 1, ri = nu & 1;                                            \
          const float* src = (ri ? wi : wr) +                                        \
            (((size_t)(c) * CH + o0 + o_l) * MODES + kxw0) * MODES;                  \
          async16(src + lane * 4, dst0 + nu * 1024 + lane * 16);                     \
        } else {                                                                     \
          int nv = nu - 8;                                                           \
          int b_l = nv >> 1, hf = nv & 1;                                            \
          const float2* src = vc + ((size_t)(b0 + b_l) * CH + (c)) * NMODE +         \
                              (u0 + hf * 4) * KY;                                    \
          async16(src + lane * 2, dst0 + 8192 + nv * 1024 + lane * 16);              \
        }                                                                            \
      }                                                                              \
    }

  STAGE(0); STAGE(1); STAGE(2);
  for (int k = 0; k < 128; ++k) {
    __builtin_amdgcn_sched_barrier(0);
    if (k < 126)       asm volatile("s_waitcnt vmcnt(8)" ::: "memory");
    else if (k == 126) asm volatile("s_waitcnt vmcnt(4)" ::: "memory");
    else               asm volatile("s_waitcnt vmcnt(0)" ::: "memory");
    __builtin_amdgcn_s_barrier();           // chunk k in LDS for ALL waves; buf k-1 free
    __builtin_amdgcn_sched_barrier(0);
    STAGE(k + 3);                           // writes buf (k-1)&3 (safe post-barrier)
    {
      const float*  Wb = (const float*)&ring[k & 3][0];
      const float2* Vb = (const float2*)((const char*)&ring[k & 3][0] + 8192);
      float2 vv[4];
      #pragma unroll
      for (int bb = 0; bb < 4; ++bb)
        vv[bb] = Vb[(bb * 2 + (u_l >> 2)) * 128 + (u_l & 3) * 32 + ky];
      #pragma unroll
      for (int oo = 0; oo < 4; ++oo) {
        float wrv = Wb[(oo * 2 + 0) * 256 + t];
        float wiv = Wb[(oo * 2 + 1) * 256 + t];
        #pragma unroll
        for (int bb = 0; bb < 4; ++bb) {
          accR[oo][bb] += wrv * vv[bb].x - wiv * vv[bb].y;
          accI[oo][bb] += wrv * vv[bb].y + wiv * vv[bb].x;
        }
      }
    }
  }
  #undef STAGE
  int u = u0 + u_l;
  #pragma unroll
  for (int oo = 0; oo < 4; ++oo)
    #pragma unroll
    for (int bb = 0; bb < 4; ++bb) {
      int o = o0 + oo, b = b0 + bb;
      oc[(((size_t)b * CH + o) * U + u) * KY + ky] = make_float2(accR[oo][bb], accI[oo][bb]);
    }
}

// ---------------- K3b: Hermitian projection of ky=0 column ----------------
__global__ __launch_bounds__(256) void k_proj0(float2* __restrict__ vc) {
  int idx = blockIdx.x * 256 + threadIdx.x;   // B*CH*33
  if (idx >= B * CH * 33) return;
  int pi = idx % 33;
  int bc = idx / 33;
  float2* base = vc + (size_t)bc * NMODE;
  if (pi == 0) {
    base[0].y = 0.f;
  } else if (pi == 32) {
    base[32 * KY].x *= 0.5f;
    base[32 * KY].y *= 0.5f;
  } else {
    int ua = pi, ub = 64 - pi;
    float2 a = base[ua * KY], b2 = base[ub * KY];
    base[ua * KY] = make_float2(0.5f * (a.x + b2.x), 0.5f * (a.y - b2.y));
    base[ub * KY] = make_float2(0.5f * (b2.x + a.x), 0.5f * (b2.y - a.y));
  }
}

// ---------------- K4: pw1 in spectral space (float2 io), XCD-pinned per batch ----------------
__global__ __launch_bounds__(256) void k_pw1(const float2* __restrict__ xc,
                                             const float* __restrict__ pw1,
                                             float2* __restrict__ hc) {
  __shared__ float wT[CH][CH + 1];
  int bid = blockIdx.x;
  int b = ((bid & 7) << 1) | ((bid >> 8) & 1);
  int jt = (bid >> 3) & 31;
  int t = threadIdx.x;
  for (int e = t; e < CH * CH; e += 256) {
    int p = e >> 7, c = e & 127;
    wT[c][p] = pw1[e];
  }
  __syncthreads();
  int tx = t & 15, ty = t >> 4;
  int j0 = jt * 64 + tx * 4;
  float accR[4][8] = {}, accI[4][8] = {};
  for (int c = 0; c < CH; ++c) {
    const float4* x4 = (const float4*)&xc[((size_t)b * CH + c) * NMODE + j0];
    float4 v0 = x4[0], v1 = x4[1];
    float xrv[4] = {v0.x, v0.z, v1.x, v1.z};
    float xiv[4] = {v0.y, v0.w, v1.y, v1.w};
    float w[8];
    #pragma unroll
    for (int pp = 0; pp < 8; ++pp) w[pp] = wT[c][ty * 8 + pp];
    #pragma unroll
    for (int jj = 0; jj < 4; ++jj)
      #pragma unroll
      for (int pp = 0; pp < 8; ++pp) {
        accR[jj][pp] += w[pp] * xrv[jj];
        accI[jj][pp] += w[pp] * xiv[jj];
      }
  }
  #pragma unroll
  for (int pp = 0; pp < 8; ++pp) {
    int p = ty * 8 + pp;
    float4* o4 = (float4*)&hc[((size_t)b * CH + p) * NMODE + j0];
    o4[0] = make_float4(accR[0][pp], accI[0][pp], accR[1][pp], accI[1][pp]);
    o4[1] = make_float4(accR[2][pp], accI[2][pp], accR[3][pp], accI[3][pp]);
  }
}

// ---------------- K5: fused iDFT + bias + gelu + pw2, parity + async dbuf ----------------
// grid = 4096: b = (bid&7)|(((bid>>3)&1)<<3) (XCD-pinned b), pg = (bid>>4)&31, xs = bid>>9.
__global__ __launch_bounds__(256) void k_idft_partial(const float2* __restrict__ hc,
                                                      const float* __restrict__ pb1,
                                                      const float* __restrict__ pw2,
                                                      float* __restrict__ partial) {
  __shared__ float2 tw[DIM];                  // 1 KB
  __shared__ float2 hfs[2][NMODE];            // 32 KB dbuf
  __shared__ float2 sbuf[16][KY];             // [x-slot][ky] 4 KB
  int bid = blockIdx.x;
  int b = (bid & 7) | (((bid >> 3) & 1) << 3);
  int pg = (bid >> 4) & 31, xs = bid >> 9;
  int x0 = xs * 8;
  int t = threadIdx.x;
  int wv = t >> 6, lane = t & 63;
  if (t < 128) {
    float ang = (float)(2.0 * M_PI) * (float)t / 128.0f;
    tw[t] = make_float2(cosf(ang), sinf(ang));
  }

  #define STAGE_H(bf, pp_)                                                           \
    {                                                                                \
      const char* srcb = (const char*)(hc + ((size_t)b * CH + pg * PPG + (pp_)) * NMODE); \
      _Pragma("unroll")                                                              \
      for (int n = 0; n < 4; ++n) {                                                  \
        int nu = wv * 4 + n;                                                         \
        async16(srcb + (size_t)nu * 1024 + lane * 16,                                \
                (char*)&hfs[bf][0] + (size_t)nu * 1024 + lane * 16);                 \
      }                                                                              \
    }

  STAGE_H(0, 0);
  __syncthreads();                            // tw + hfs[0] ready
  int y = t & 63, xh = t >> 6;
  float Cr[KY], Sr[KY];
  #pragma unroll
  for (int ky = 0; ky < KY; ++ky) {
    float2 w = tw[(ky * y) & 127];
    float wk = (ky == 0) ? 1.f : 2.f;
    Cr[ky] = wk * w.x;
    Sr[ky] = -wk * w.y;
  }
  int xqA = t >> 5, kyA = t & 31;
  int xA = x0 + xqA;
  float res[8] = {0.f, 0.f, 0.f, 0.f, 0.f, 0.f, 0.f, 0.f};
  for (int pp = 0; pp < PPG; ++pp) {
    int p = pg * PPG + pp;
    int cur = pp & 1;
    if (pp) __syncthreads();                  // hfs[cur] staged; sbuf free
    if (pp + 1 < PPG) STAGE_H(cur ^ 1, pp + 1);
    // phase A with u-parity: s[x]=Pe+Po, s[x+64]=Pe-Po; independent tt per iter
    {
      float per = 0.f, pei = 0.f, por = 0.f, poi = 0.f;
      #pragma unroll
      for (int uu = 0; uu < 32; uu += 2) {
        float2 w0 = tw[(uu * xA) & 127];
        float2 h0 = hfs[cur][uu * KY + kyA];
        per += h0.x * w0.x - h0.y * w0.y;
        pei += h0.x * w0.y + h0.y * w0.x;
        float2 w1 = tw[((uu + 1) * xA) & 127];
        float2 h1 = hfs[cur][(uu + 1) * KY + kyA];
        por += h1.x * w1.x - h1.y * w1.y;
        poi += h1.x * w1.y + h1.y * w1.x;
      }
      #pragma unroll
      for (int uu = 32; uu < 64; uu += 2) {
        float2 w0 = tw[((uu + 64) * xA) & 127];
        float2 h0 = hfs[cur][uu * KY + kyA];
        per += h0.x * w0.x - h0.y * w0.y;
        pei += h0.x * w0.y + h0.y * w0.x;
        float2 w1 = tw[((uu + 65) * xA) & 127];
        float2 h1 = hfs[cur][(uu + 1) * KY + kyA];
        por += h1.x * w1.x - h1.y * w1.y;
        poi += h1.x * w1.y + h1.y * w1.x;
      }
      sbuf[xqA][kyA]     = make_float2(per + por, pei + poi);
      sbuf[xqA + 8][kyA] = make_float2(per - por, pei - poi);
    }
    __syncthreads();
    // phase B with ky-parity: out[y] = Ae+Ao, out[y+64] = Ae-Ao (float4 sbuf reads)
    float pb = pb1[p], pw = pw2[p];
    #pragma unroll
    for (int sl = 0; sl < 4; ++sl) {
      int s_i = xh + sl * 4;
      float ae = 0.f, ao = 0.f;
      #pragma unroll
      for (int ky = 0; ky < KY; ky += 2) {
        float4 v = *(const float4*)&sbuf[s_i][ky];   // {re_ky, im_ky, re_ky1, im_ky1}
        ae += v.x * Cr[ky] + v.y * Sr[ky];
        ao += v.z * Cr[ky + 1] + v.w * Sr[ky + 1];
      }
      float hlo = (ae + ao) * (1.f / 16384.f) + pb;
      float hhi = (ae - ao) * (1.f / 16384.f) + pb;
      float zlo = 1.5957691216057308f * (hlo + 0.044715f * hlo * hlo * hlo);
      float zhi = 1.5957691216057308f * (hhi + 0.044715f * hhi * hhi * hhi);
      res[sl * 2]     += pw * hlo * __builtin_amdgcn_rcpf(1.f + __expf(-zlo));
      res[sl * 2 + 1] += pw * hhi * __builtin_amdgcn_rcpf(1.f + __expf(-zhi));
    }
  }
  #undef STAGE_H
  size_t pbase = ((size_t)pg * B + b) * N2;
  #pragma unroll
  for (int sl = 0; sl < 4; ++sl) {
    int s_i = xh + sl * 4;
    int x = x0 + (s_i & 7) + ((s_i >> 3) << 6);
    partial[pbase + x * DIM + y]      = res[sl * 2];
    partial[pbase + x * DIM + y + 64] = res[sl * 2 + 1];
  }
}

// ---------------- K6: reduce p-group partials + pb2 ----------------
__global__ __launch_bounds__(256) void k_reduce(const float* __restrict__ partial,
                                                const float* __restrict__ pb2,
                                                float* __restrict__ outp) {
  int idx = blockIdx.x * 256 + threadIdx.x;
  if (idx >= B * N2) return;
  float s = pb2[0];
  #pragma unroll
  for (int pg = 0; pg < PG; ++pg) s += partial[(size_t)pg * B * N2 + idx];
  outp[idx] = s;
}

extern "C" void kernel_launch(void* const* d_in, const int* in_sizes, int n_in,
                              void* d_out, int out_size, void* d_ws, size_t ws_size,
                              hipStream_t stream) {
  const float* z   = (const float*)d_in[0];
  const float* lw  = (const float*)d_in[1];
  const float* lb  = (const float*)d_in[2];
  const float* wr1 = (const float*)d_in[3];
  const float* wi1 = (const float*)d_in[4];
  const float* wr2 = (const float*)d_in[5];
  const float* wi2 = (const float*)d_in[6];
  const float* pw1 = (const float*)d_in[7];
  const float* pb1 = (const float*)d_in[8];
  const float* pw2 = (const float*)d_in[9];
  const float* pb2 = (const float*)d_in[10];
  float* out = (float*)d_out;
  float* ws = (float*)d_ws;

  float* zfr = ws;
  float* zfi = zfr + 32768;
  float2* Ac = (float2*)(ws + 65536);
  float2* Bc = Ac + (size_t)B * CH * NMODE;
  float2* t1 = Bc;   // aliases Bc (dead until first k_spec write)

  k_zf1<<<B * 8, 256, 0, stream>>>(z, t1);
  k_zf2<<<B * 2, 256, 0, stream>>>(t1, zfr, zfi);
  k_lift<<<(B * CH * NMODE) / 256, 256, 0, stream>>>(zfr, zfi, lw, lb, Ac);

  const size_t WSTRIDE = (size_t)CH * CH * MODES * MODES;
  float2 *ir = Ac, *oc = Bc;
  for (int l = 0; l < NLAYERS; ++l) {
    k_spec<<<1024, 256, 0, stream>>>(ir,
                                     wr1 + l * WSTRIDE, wi1 + l * WSTRIDE,
                                     wr2 + l * WSTRIDE, wi2 + l * WSTRIDE,
                                     oc);
    if (l < NLAYERS - 1)
      k_proj0<<<(B * CH * 33 + 255) / 256, 256, 0, stream>>>(oc);
    float2* tmp = ir; ir = oc; oc = tmp;
  }
  k_pw1<<<512, 256, 0, stream>>>(ir, pw1, oc);
  float* partial = (float*)ir;   // aliases Ac (33.5 MB < 67 MB, dead after k_pw1)
  k_idft_partial<<<B * PG * 8, 256, 0, stream>>>(oc, pb1, pw2, partial);
  k_reduce<<<(B * N2) / 256, 256, 0, stream>>>(partial, pb2, out);
}

// Round 12
// 915.344 us; speedup vs baseline: 1.4644x; 1.4644x over previous
//
#include <hip/hip_runtime.h>
#include <math.h>

#define B 16
#define CH 128
#define DIM 128
#define MODES 32
#define NLAYERS 4
#define PROJ 128
#define U 64            // stored kx modes: u<32 -> kx=u ; u>=32 -> kx=u+64 (96..127)
#define KY 32
#define NMODE (U*KY)    // 2048
#define N2 (DIM*DIM)    // 16384
#define PG 32           // p-groups in idft
#define PPG (PROJ/PG)   // 4 p per group

__device__ __forceinline__ void async16(const void* g, void* l) {
  __builtin_amdgcn_global_load_lds((const __attribute__((address_space(1))) unsigned int*)g,
                                   (__attribute__((address_space(3))) unsigned int*)l, 16, 0, 0);
}

// ---------------- K1a: t1[b][x][ky] = sum_y z[b][x][y] e^{-2pi i ky y/128} ----------------
__global__ __launch_bounds__(256) void k_zf1(const float* __restrict__ z,
                                             float2* __restrict__ t1) {
  __shared__ float zrow[16][DIM];
  __shared__ float2 tw[DIM];
  int bid = blockIdx.x;
  int b = bid >> 3, xt = bid & 7;
  int x0 = xt * 16;
  int t = threadIdx.x;
  if (t < 128) {
    float ang = (float)(2.0 * M_PI) * (float)t / 128.0f;
    tw[t] = make_float2(cosf(ang), sinf(ang));
  }
  for (int e = t; e < 16 * DIM / 4; e += 256)
    ((float4*)&zrow[0][0])[e] = ((const float4*)&z[b * N2 + x0 * DIM])[e];
  __syncthreads();
  #pragma unroll
  for (int j = 0; j < 2; ++j) {
    int it = t + j * 256;
    int x_l = it >> 5, ky = it & 31;
    float tr = 0.f, ti = 0.f;
    for (int y = 0; y < DIM; ++y) {
      float v = zrow[x_l][y];
      float2 w = tw[(ky * y) & 127];
      tr += v * w.x;
      ti -= v * w.y;
    }
    t1[((size_t)b * DIM + x0 + x_l) * KY + ky] = make_float2(tr, ti);
  }
}

// ---------------- K1b: zf[b][u][ky] = sum_x t1[b][x][ky] e^{-2pi i kx x/128} ----------------
__global__ __launch_bounds__(256) void k_zf2(const float2* __restrict__ t1,
                                             float* __restrict__ zfr, float* __restrict__ zfi) {
  __shared__ float2 t1s[DIM][KY];
  __shared__ float2 tw[DIM];
  int bid = blockIdx.x;
  int b = bid >> 1, uh = bid & 1;
  int t = threadIdx.x;
  if (t < 128) {
    float ang = (float)(2.0 * M_PI) * (float)t / 128.0f;
    tw[t] = make_float2(cosf(ang), sinf(ang));
  }
  for (int e = t; e < DIM * KY / 2; e += 256)
    ((float4*)&t1s[0][0])[e] = ((const float4*)&t1[(size_t)b * DIM * KY])[e];
  __syncthreads();
  #pragma unroll
  for (int j = 0; j < 4; ++j) {
    int m = t + j * 256;
    int u_l = m >> 5, ky = m & 31;
    int u = uh * 32 + u_l;
    int kx = (u < 32) ? u : (u + 64);
    float ar = 0.f, ai = 0.f;
    for (int x = 0; x < DIM; ++x) {
      float2 v = t1s[x][ky];
      float2 w = tw[(kx * x) & 127];
      ar += v.x * w.x + v.y * w.y;
      ai += v.y * w.x - v.x * w.y;
    }
    zfr[b * NMODE + u * KY + ky] = ar;
    zfi[b * NMODE + u * KY + ky] = ai;
  }
}

// ---------------- K2: lift in spectral space (float2 out) ----------------
__global__ __launch_bounds__(256) void k_lift(const float* __restrict__ zfr, const float* __restrict__ zfi,
                                              const float* __restrict__ lw, const float* __restrict__ lb,
                                              float2* __restrict__ vcout) {
  int idx = blockIdx.x * 256 + threadIdx.x;
  if (idx >= B * CH * NMODE) return;
  int m = idx & (NMODE - 1);
  int c = (idx >> 11) & 127;
  int b = idx >> 18;
  float w = lw[c];
  float re = w * zfr[b * NMODE + m];
  float im = w * zfi[b * NMODE + m];
  if (m == 0) re += 16384.f * lb[c];
  vcout[idx] = make_float2(re, im);
}

// ---------------- K3: spectral einsum, one layer ----------------
// grid = 1024: u = ((bid&7)<<3)|((bid>>3)&7) (same-u -> same XCD; V slice L2-hot),
// ot = bid>>6 (16 o-tiles of 8). All 16 b per block -> W read from HBM exactly once.
// chunk = 2 i = 12 KB (W 4 KB units 0..3, V 8 KB units 0..7); ring-4 (48 KB -> 3 blocks/CU);
// counted vmcnt: every wave issues exactly 3 async16/chunk -> depth-3 = vmcnt(6).
__global__ __launch_bounds__(256) void k_spec(const float2* __restrict__ vc,
                                              const float* __restrict__ wr1, const float* __restrict__ wi1,
                                              const float* __restrict__ wr2, const float* __restrict__ wi2,
                                              float2* __restrict__ oc) {
  __shared__ float4 ring[4][768];           // 4 x 12 KB
  int bid = blockIdx.x;
  int u = ((bid & 7) << 3) | ((bid >> 3) & 7);
  int ot = bid >> 6;
  int o0 = ot * 8;
  int kxw = u & 31;
  const float* wr = (u >= 32) ? wr2 : wr1;
  const float* wi = (u >= 32) ? wi2 : wi1;
  int t = threadIdx.x;
  int ky = t & 31, bh = (t >> 5) & 1, oq = t >> 6;   // oq = wave id 0..3
  int wv = t >> 6, lane = t & 63;
  float accR[2][8] = {}, accI[2][8] = {};

  #define STAGE(c)                                                                   \
    if ((c) < 64) {                                                                  \
      char* dst0 = (char*)&ring[0][0] + (size_t)((c) & 3) * 12288;                   \
      int i0_ = (c) * 2;                                                             \
      _Pragma("unroll")                                                              \
      for (int n = 0; n < 3; ++n) {                                                  \
        int nu = wv * 3 + n;                                                         \
        if (nu < 4) {                                                                \
          int ri = nu >> 1, il = nu & 1;                                             \
          int o_l = lane >> 3, ky4 = (lane & 7) * 4;                                 \
          const float* src = (ri ? wi : wr) +                                        \
            (((size_t)(i0_ + il) * CH + o0 + o_l) * MODES + kxw) * MODES + ky4;      \
          async16(src, dst0 + nu * 1024 + lane * 16);                                \
        } else {                                                                     \
          int nv = nu - 4;                                                           \
          int il = nv >> 2;                                                          \
          int b_l = (nv & 3) * 4 + (lane >> 4), ky2 = (lane & 15) * 2;               \
          const float2* src = vc + ((size_t)b_l * CH + i0_ + il) * NMODE +           \
                              u * KY + ky2;                                          \
          async16(src, dst0 + 4096 + nv * 1024 + lane * 16);                         \
        }                                                                            \
      }                                                                              \
    }

  STAGE(0); STAGE(1); STAGE(2);
  for (int k = 0; k < 64; ++k) {
    __builtin_amdgcn_sched_barrier(0);
    if (k < 62)       asm volatile("s_waitcnt vmcnt(6)" ::: "memory");
    else if (k == 62) asm volatile("s_waitcnt vmcnt(3)" ::: "memory");
    else              asm volatile("s_waitcnt vmcnt(0)" ::: "memory");
    __builtin_amdgcn_s_barrier();           // chunk k in LDS for ALL waves; buf k-1 free
    __builtin_amdgcn_sched_barrier(0);
    STAGE(k + 3);                           // writes buf (k+3)&3 = (k-1)&3 (safe post-barrier)
    {
      const char* dstc = (const char*)&ring[0][0] + (size_t)(k & 3) * 12288;
      const float*  Wb = (const float*)dstc;
      const float2* Vb = (const float2*)(dstc + 4096);
      #pragma unroll
      for (int il = 0; il < 2; ++il) {
        float wrv[2], wiv[2];
        #pragma unroll
        for (int j = 0; j < 2; ++j) {
          wrv[j] = Wb[il * 256 + (oq * 2 + j) * 32 + ky];
          wiv[j] = Wb[(2 + il) * 256 + (oq * 2 + j) * 32 + ky];
        }
        #pragma unroll
        for (int bb = 0; bb < 8; ++bb) {
          int b = bh * 8 + bb;
          float2 v = Vb[il * 512 + (b >> 2) * 128 + (b & 3) * 32 + ky];
          #pragma unroll
          for (int j = 0; j < 2; ++j) {
            accR[j][bb] += wrv[j] * v.x - wiv[j] * v.y;
            accI[j][bb] += wrv[j] * v.y + wiv[j] * v.x;
          }
        }
      }
    }
  }
  #undef STAGE
  #pragma unroll
  for (int j = 0; j < 2; ++j)
    #pragma unroll
    for (int bb = 0; bb < 8; ++bb) {
      int o = o0 + oq * 2 + j, b = bh * 8 + bb;
      oc[(((size_t)b * CH + o) * U + u) * KY + ky] = make_float2(accR[j][bb], accI[j][bb]);
    }
}

// ---------------- K3b: Hermitian projection of ky=0 column ----------------
__global__ __launch_bounds__(256) void k_proj0(float2* __restrict__ vc) {
  int idx = blockIdx.x * 256 + threadIdx.x;   // B*CH*33
  if (idx >= B * CH * 33) return;
  int pi = idx % 33;
  int bc = idx / 33;
  float2* base = vc + (size_t)bc * NMODE;
  if (pi == 0) {
    base[0].y = 0.f;
  } else if (pi == 32) {
    base[32 * KY].x *= 0.5f;
    base[32 * KY].y *= 0.5f;
  } else {
    int ua = pi, ub = 64 - pi;
    float2 a = base[ua * KY], b2 = base[ub * KY];
    base[ua * KY] = make_float2(0.5f * (a.x + b2.x), 0.5f * (a.y - b2.y));
    base[ub * KY] = make_float2(0.5f * (b2.x + a.x), 0.5f * (b2.y - a.y));
  }
}

// ---------------- K4: pw1 in spectral space (float2 io), XCD-pinned per batch ----------------
__global__ __launch_bounds__(256) void k_pw1(const float2* __restrict__ xc,
                                             const float* __restrict__ pw1,
                                             float2* __restrict__ hc) {
  __shared__ float wT[CH][CH + 1];
  int bid = blockIdx.x;
  int b = ((bid & 7) << 1) | ((bid >> 8) & 1);
  int jt = (bid >> 3) & 31;
  int t = threadIdx.x;
  for (int e = t; e < CH * CH; e += 256) {
    int p = e >> 7, c = e & 127;
    wT[c][p] = pw1[e];
  }
  __syncthreads();
  int tx = t & 15, ty = t >> 4;
  int j0 = jt * 64 + tx * 4;
  float accR[4][8] = {}, accI[4][8] = {};
  for (int c = 0; c < CH; ++c) {
    const float4* x4 = (const float4*)&xc[((size_t)b * CH + c) * NMODE + j0];
    float4 v0 = x4[0], v1 = x4[1];
    float xrv[4] = {v0.x, v0.z, v1.x, v1.z};
    float xiv[4] = {v0.y, v0.w, v1.y, v1.w};
    float w[8];
    #pragma unroll
    for (int pp = 0; pp < 8; ++pp) w[pp] = wT[c][ty * 8 + pp];
    #pragma unroll
    for (int jj = 0; jj < 4; ++jj)
      #pragma unroll
      for (int pp = 0; pp < 8; ++pp) {
        accR[jj][pp] += w[pp] * xrv[jj];
        accI[jj][pp] += w[pp] * xiv[jj];
      }
  }
  #pragma unroll
  for (int pp = 0; pp < 8; ++pp) {
    int p = ty * 8 + pp;
    float4* o4 = (float4*)&hc[((size_t)b * CH + p) * NMODE + j0];
    o4[0] = make_float4(accR[0][pp], accI[0][pp], accR[1][pp], accI[1][pp]);
    o4[1] = make_float4(accR[2][pp], accI[2][pp], accR[3][pp], accI[3][pp]);
  }
}

// ---------------- K5: fused iDFT + bias + gelu + pw2, parity + async dbuf + E-tile ----------------
// grid = 4096: b = (bid&7)|(((bid>>3)&1)<<3) (XCD-pinned b), pg = (bid>>4)&31, xs = bid>>9.
// sE[xq][j] = (cos,sin) of even-u and odd-u twiddles, precomputed ONCE per block:
// removes per-iteration index math + tw lookups from the hot p-loop.
__global__ __launch_bounds__(256) void k_idft_partial(const float2* __restrict__ hc,
                                                      const float* __restrict__ pb1,
                                                      const float* __restrict__ pw2,
                                                      float* __restrict__ partial) {
  __shared__ float2 tw[DIM];                  // 1 KB
  __shared__ float2 hfs[2][NMODE];            // 32 KB dbuf
  __shared__ float2 sbuf[16][KY];             // [x-slot][ky] 4 KB
  __shared__ float4 sE[8][32];                // E-tile 4 KB
  int bid = blockIdx.x;
  int b = (bid & 7) | (((bid >> 3) & 1) << 3);
  int pg = (bid >> 4) & 31, xs = bid >> 9;
  int x0 = xs * 8;
  int t = threadIdx.x;
  int wv = t >> 6, lane = t & 63;
  if (t < 128) {
    float ang = (float)(2.0 * M_PI) * (float)t / 128.0f;
    tw[t] = make_float2(cosf(ang), sinf(ang));
  }

  #define STAGE_H(bf, pp_)                                                           \
    {                                                                                \
      const char* srcb = (const char*)(hc + ((size_t)b * CH + pg * PPG + (pp_)) * NMODE); \
      _Pragma("unroll")                                                              \
      for (int n = 0; n < 4; ++n) {                                                  \
        int nu = wv * 4 + n;                                                         \
        async16(srcb + (size_t)nu * 1024 + lane * 16,                                \
                (char*)&hfs[bf][0] + (size_t)nu * 1024 + lane * 16);                 \
      }                                                                              \
    }

  STAGE_H(0, 0);
  __syncthreads();                            // tw + hfs[0] ready
  // E-tile: for x-slot xq, pair j: even u = 2j (kx = 2j or 2j+64), odd u = 2j+1
  {
    int xq = t >> 5, j = t & 31;
    int x = x0 + xq;
    int kxE = (j < 16) ? (2 * j) : (2 * j + 64);
    float2 wE = tw[(kxE * x) & 127];
    float2 wO = tw[((kxE + 1) * x) & 127];
    sE[xq][j] = make_float4(wE.x, wE.y, wO.x, wO.y);
  }
  int y = t & 63, xh = t >> 6;
  float Cr[KY], Sr[KY];
  #pragma unroll
  for (int ky = 0; ky < KY; ++ky) {
    float2 w = tw[(ky * y) & 127];
    float wk = (ky == 0) ? 1.f : 2.f;
    Cr[ky] = wk * w.x;
    Sr[ky] = -wk * w.y;
  }
  __syncthreads();                            // sE visible to all
  int xqA = t >> 5, kyA = t & 31;
  float res[8] = {0.f, 0.f, 0.f, 0.f, 0.f, 0.f, 0.f, 0.f};
  for (int pp = 0; pp < PPG; ++pp) {
    int p = pg * PPG + pp;
    int cur = pp & 1;
    if (pp) __syncthreads();                  // hfs[cur] staged; sbuf free
    if (pp + 1 < PPG) STAGE_H(cur ^ 1, pp + 1);
    // phase A with u-parity via E-tile: s[x]=Pe+Po, s[x+64]=Pe-Po
    {
      float per = 0.f, pei = 0.f, por = 0.f, poi = 0.f;
      #pragma unroll
      for (int j = 0; j < 32; ++j) {
        float4 E = sE[xqA][j];
        float2 h0 = hfs[cur][(2 * j) * KY + kyA];
        float2 h1 = hfs[cur][(2 * j + 1) * KY + kyA];
        per += h0.x * E.x - h0.y * E.y;
        pei += h0.x * E.y + h0.y * E.x;
        por += h1.x * E.z - h1.y * E.w;
        poi += h1.x * E.w + h1.y * E.z;
      }
      sbuf[xqA][kyA]     = make_float2(per + por, pei + poi);
      sbuf[xqA + 8][kyA] = make_float2(per - por, pei - poi);
    }
    __syncthreads();
    // phase B with ky-parity: out[y] = Ae+Ao, out[y+64] = Ae-Ao (float4 sbuf reads)
    float pb = pb1[p], pw = pw2[p];
    #pragma unroll
    for (int sl = 0; sl < 4; ++sl) {
      int s_i = xh + sl * 4;
      float ae = 0.f, ao = 0.f;
      #pragma unroll
      for (int ky = 0; ky < KY; ky += 2) {
        float4 v = *(const float4*)&sbuf[s_i][ky];   // {re_ky, im_ky, re_ky1, im_ky1}
        ae += v.x * Cr[ky] + v.y * Sr[ky];
        ao += v.z * Cr[ky + 1] + v.w * Sr[ky + 1];
      }
      float hlo = (ae + ao) * (1.f / 16384.f) + pb;
      float hhi = (ae - ao) * (1.f / 16384.f) + pb;
      float zlo = 1.5957691216057308f * (hlo + 0.044715f * hlo * hlo * hlo);
      float zhi = 1.5957691216057308f * (hhi + 0.044715f * hhi * hhi * hhi);
      res[sl * 2]     += pw * hlo * __builtin_amdgcn_rcpf(1.f + __expf(-zlo));
      res[sl * 2 + 1] += pw * hhi * __builtin_amdgcn_rcpf(1.f + __expf(-zhi));
    }
  }
  #undef STAGE_H
  size_t pbase = ((size_t)pg * B + b) * N2;
  #pragma unroll
  for (int sl = 0; sl < 4; ++sl) {
    int s_i = xh + sl * 4;
    int x = x0 + (s_i & 7) + ((s_i >> 3) << 6);
    partial[pbase + x * DIM + y]      = res[sl * 2];
    partial[pbase + x * DIM + y + 64] = res[sl * 2 + 1];
  }
}

// ---------------- K6: reduce p-group partials + pb2 ----------------
__global__ __launch_bounds__(256) void k_reduce(const float* __restrict__ partial,
                                                const float* __restrict__ pb2,
                                                float* __restrict__ outp) {
  int idx = blockIdx.x * 256 + threadIdx.x;
  if (idx >= B * N2) return;
  float s = pb2[0];
  #pragma unroll
  for (int pg = 0; pg < PG; ++pg) s += partial[(size_t)pg * B * N2 + idx];
  outp[idx] = s;
}

extern "C" void kernel_launch(void* const* d_in, const int* in_sizes, int n_in,
                              void* d_out, int out_size, void* d_ws, size_t ws_size,
                              hipStream_t stream) {
  const float* z   = (const float*)d_in[0];
  const float* lw  = (const float*)d_in[1];
  const float* lb  = (const float*)d_in[2];
  const float* wr1 = (const float*)d_in[3];
  const float* wi1 = (const float*)d_in[4];
  const float* wr2 = (const float*)d_in[5];
  const float* wi2 = (const float*)d_in[6];
  const float* pw1 = (const float*)d_in[7];
  const float* pb1 = (const float*)d_in[8];
  const float* pw2 = (const float*)d_in[9];
  const float* pb2 = (const float*)d_in[10];
  float* out = (float*)d_out;
  float* ws = (float*)d_ws;

  float* zfr = ws;
  float* zfi = zfr + 32768;
  float2* Ac = (float2*)(ws + 65536);
  float2* Bc = Ac + (size_t)B * CH * NMODE;
  float2* t1 = Bc;   // aliases Bc (dead until first k_spec write)

  k_zf1<<<B * 8, 256, 0, stream>>>(z, t1);
  k_zf2<<<B * 2, 256, 0, stream>>>(t1, zfr, zfi);
  k_lift<<<(B * CH * NMODE) / 256, 256, 0, stream>>>(zfr, zfi, lw, lb, Ac);

  const size_t WSTRIDE = (size_t)CH * CH * MODES * MODES;
  float2 *ir = Ac, *oc = Bc;
  for (int l = 0; l < NLAYERS; ++l) {
    k_spec<<<1024, 256, 0, stream>>>(ir,
                                     wr1 + l * WSTRIDE, wi1 + l * WSTRIDE,
                                     wr2 + l * WSTRIDE, wi2 + l * WSTRIDE,
                                     oc);
    if (l < NLAYERS - 1)
      k_proj0<<<(B * CH * 33 + 255) / 256, 256, 0, stream>>>(oc);
    float2* tmp = ir; ir = oc; oc = tmp;
  }
  k_pw1<<<512, 256, 0, stream>>>(ir, pw1, oc);
  float* partial = (float*)ir;   // aliases Ac (33.5 MB < 67 MB, dead after k_pw1)
  k_idft_partial<<<B * PG * 8, 256, 0, stream>>>(oc, pb1, pw2, partial);
  k_reduce<<<(B * N2) / 256, 256, 0, stream>>>(partial, pb2, out);
}

// Round 13
// 791.773 us; speedup vs baseline: 1.6930x; 1.1561x over previous
//
#include <hip/hip_runtime.h>
#include <math.h>

#define B 16
#define CH 128
#define DIM 128
#define MODES 32
#define NLAYERS 4
#define PROJ 128
#define U 64            // stored kx modes: u<32 -> kx=u ; u>=32 -> kx=u+64 (96..127)
#define KY 32
#define NMODE (U*KY)    // 2048
#define N2 (DIM*DIM)    // 16384
#define PG 32           // p-groups in idft
#define PPG (PROJ/PG)   // 4 p per group

__device__ __forceinline__ void async16(const void* g, void* l) {
  __builtin_amdgcn_global_load_lds((const __attribute__((address_space(1))) unsigned int*)g,
                                   (__attribute__((address_space(3))) unsigned int*)l, 16, 0, 0);
}

// ---------------- K1a: t1[b][x][ky] = sum_y z[b][x][y] e^{-2pi i ky y/128} ----------------
__global__ __launch_bounds__(256) void k_zf1(const float* __restrict__ z,
                                             float2* __restrict__ t1) {
  __shared__ float zrow[16][DIM];
  __shared__ float2 tw[DIM];
  int bid = blockIdx.x;
  int b = bid >> 3, xt = bid & 7;
  int x0 = xt * 16;
  int t = threadIdx.x;
  if (t < 128) {
    float ang = (float)(2.0 * M_PI) * (float)t / 128.0f;
    tw[t] = make_float2(cosf(ang), sinf(ang));
  }
  for (int e = t; e < 16 * DIM / 4; e += 256)
    ((float4*)&zrow[0][0])[e] = ((const float4*)&z[b * N2 + x0 * DIM])[e];
  __syncthreads();
  #pragma unroll
  for (int j = 0; j < 2; ++j) {
    int it = t + j * 256;
    int x_l = it >> 5, ky = it & 31;
    float tr = 0.f, ti = 0.f;
    for (int y = 0; y < DIM; ++y) {
      float v = zrow[x_l][y];
      float2 w = tw[(ky * y) & 127];
      tr += v * w.x;
      ti -= v * w.y;
    }
    t1[((size_t)b * DIM + x0 + x_l) * KY + ky] = make_float2(tr, ti);
  }
}

// ---------------- K1b: zf[b][u][ky] = sum_x t1[b][x][ky] e^{-2pi i kx x/128} ----------------
__global__ __launch_bounds__(256) void k_zf2(const float2* __restrict__ t1,
                                             float* __restrict__ zfr, float* __restrict__ zfi) {
  __shared__ float2 t1s[DIM][KY];
  __shared__ float2 tw[DIM];
  int bid = blockIdx.x;
  int b = bid >> 1, uh = bid & 1;
  int t = threadIdx.x;
  if (t < 128) {
    float ang = (float)(2.0 * M_PI) * (float)t / 128.0f;
    tw[t] = make_float2(cosf(ang), sinf(ang));
  }
  for (int e = t; e < DIM * KY / 2; e += 256)
    ((float4*)&t1s[0][0])[e] = ((const float4*)&t1[(size_t)b * DIM * KY])[e];
  __syncthreads();
  #pragma unroll
  for (int j = 0; j < 4; ++j) {
    int m = t + j * 256;
    int u_l = m >> 5, ky = m & 31;
    int u = uh * 32 + u_l;
    int kx = (u < 32) ? u : (u + 64);
    float ar = 0.f, ai = 0.f;
    for (int x = 0; x < DIM; ++x) {
      float2 v = t1s[x][ky];
      float2 w = tw[(kx * x) & 127];
      ar += v.x * w.x + v.y * w.y;
      ai += v.y * w.x - v.x * w.y;
    }
    zfr[b * NMODE + u * KY + ky] = ar;
    zfi[b * NMODE + u * KY + ky] = ai;
  }
}

// ---------------- K2: lift in spectral space (float2 out) ----------------
__global__ __launch_bounds__(256) void k_lift(const float* __restrict__ zfr, const float* __restrict__ zfi,
                                              const float* __restrict__ lw, const float* __restrict__ lb,
                                              float2* __restrict__ vcout) {
  int idx = blockIdx.x * 256 + threadIdx.x;
  if (idx >= B * CH * NMODE) return;
  int m = idx & (NMODE - 1);
  int c = (idx >> 11) & 127;
  int b = idx >> 18;
  float w = lw[c];
  float re = w * zfr[b * NMODE + m];
  float im = w * zfi[b * NMODE + m];
  if (m == 0) re += 16384.f * lb[c];
  vcout[idx] = make_float2(re, im);
}

// ---------------- K3: spectral einsum, one layer (round-10 best-known config) ----------------
// grid = 512: u = ((bid&7)<<3)|((bid>>3)&7) (same-u -> same XCD), ot = bid>>6 (8 o-tiles of 16).
// Each block covers ALL 16 batches -> W read exactly once from HBM.
// chunk = 2 i = 16 KB [W 8KB | V 8KB]; ring-4 (64 KB); counted vmcnt:
// every wave issues exactly 4 async16/chunk -> depth-3 = vmcnt(8).
__global__ __launch_bounds__(256) void k_spec(const float2* __restrict__ vc,
                                              const float* __restrict__ wr1, const float* __restrict__ wi1,
                                              const float* __restrict__ wr2, const float* __restrict__ wi2,
                                              float2* __restrict__ oc) {
  __shared__ float4 ring4[4][1024];         // 4 bufs x 16 KB: [W 8KB | V 8KB]
  int bid = blockIdx.x;
  int u = ((bid & 7) << 3) | ((bid >> 3) & 7);
  int ot = bid >> 6;
  int o0 = ot * 16;
  int kxw = u & 31;
  const float* wr = (u >= 32) ? wr2 : wr1;
  const float* wi = (u >= 32) ? wi2 : wi1;
  int t = threadIdx.x;
  int ky = t & 31, bh = (t >> 5) & 1, wv = t >> 6;   // wv = wave id 0..3
  int lane = t & 63;
  float accR[4][8] = {}, accI[4][8] = {};

  // Stage chunk c (2 i's) into buf c&3. Waves 0,1: W units 0..7; waves 2,3: V units 0..7.
  #define STAGE(c)                                                                   \
    if ((c) < 64) {                                                                  \
      int bf_ = (c) & 3;                                                             \
      int i0_ = (c) * 2;                                                             \
      char* dst0 = (char*)&ring4[0][0] + (size_t)bf_ * 16384;                        \
      _Pragma("unroll")                                                              \
      for (int n = 0; n < 4; ++n) {                                                  \
        int nu = wv * 4 + n;                                                         \
        if (nu < 8) {                                                                \
          int row = nu * 8 + (lane >> 3);            /* [ri][il][o] */               \
          int ri = row >> 5, il = (row >> 4) & 1, o_l = row & 15;                    \
          int ky4 = (lane & 7) * 4;                                                  \
          const float* src = (ri ? wi : wr) +                                        \
            (((size_t)(i0_ + il) * CH + o0 + o_l) * MODES + kxw) * MODES + ky4;      \
          async16(src, dst0 + (size_t)nu * 1024 + lane * 16);                        \
        } else {                                                                     \
          int nv = nu - 8;                                                           \
          int row = nv * 4 + (lane >> 4);            /* [il][b] */                   \
          int il = row >> 4, bl = row & 15;                                          \
          int ky2 = (lane & 15) * 2;                                                 \
          const float2* src = vc + ((size_t)bl * CH + i0_ + il) * NMODE +            \
                              u * KY + ky2;                                          \
          async16(src, dst0 + 8192 + (size_t)nv * 1024 + lane * 16);                 \
        }                                                                            \
      }                                                                              \
    }

  #define COMPUTE(bf_)                                                               \
    {                                                                                \
      const float*  Wb = (const float*)((const char*)&ring4[0][0] + (size_t)(bf_) * 16384); \
      const float2* Vb = (const float2*)((const char*)&ring4[0][0] + (size_t)(bf_) * 16384 + 8192); \
      _Pragma("unroll")                                                              \
      for (int il = 0; il < 2; ++il) {                                               \
        float wrv[4], wiv[4];                                                        \
        _Pragma("unroll")                                                            \
        for (int j = 0; j < 4; ++j) {                                                \
          wrv[j] = Wb[(il * 16 + wv * 4 + j) * 32 + ky];                             \
          wiv[j] = Wb[((2 + il) * 16 + wv * 4 + j) * 32 + ky];                       \
        }                                                                            \
        _Pragma("unroll")                                                            \
        for (int bb = 0; bb < 8; ++bb) {                                             \
          float2 v = Vb[(il * 16 + bh * 8 + bb) * 32 + ky];                          \
          _Pragma("unroll")                                                          \
          for (int j = 0; j < 4; ++j) {                                              \
            accR[j][bb] += wrv[j] * v.x - wiv[j] * v.y;                              \
            accI[j][bb] += wrv[j] * v.y + wiv[j] * v.x;                              \
          }                                                                          \
        }                                                                            \
      }                                                                              \
    }

  STAGE(0); STAGE(1); STAGE(2);
  for (int k = 0; k < 64; ++k) {
    __builtin_amdgcn_sched_barrier(0);
    if (k < 62)       asm volatile("s_waitcnt vmcnt(8)" ::: "memory");
    else if (k == 62) asm volatile("s_waitcnt vmcnt(4)" ::: "memory");
    else              asm volatile("s_waitcnt vmcnt(0)" ::: "memory");
    __builtin_amdgcn_s_barrier();           // all waves: chunk k in LDS; compute k-1 done
    __builtin_amdgcn_sched_barrier(0);
    STAGE(k + 3);                           // overwrites buf of chunk k-1 (safe)
    COMPUTE(k & 3);
  }
  #undef STAGE
  #undef COMPUTE
  #pragma unroll
  for (int j = 0; j < 4; ++j)
    #pragma unroll
    for (int bb = 0; bb < 8; ++bb) {
      int o = o0 + wv * 4 + j, b = bh * 8 + bb;
      oc[(((size_t)b * CH + o) * U + u) * KY + ky] = make_float2(accR[j][bb], accI[j][bb]);
    }
}

// ---------------- K3b: Hermitian projection of ky=0 column ----------------
__global__ __launch_bounds__(256) void k_proj0(float2* __restrict__ vc) {
  int idx = blockIdx.x * 256 + threadIdx.x;   // B*CH*33
  if (idx >= B * CH * 33) return;
  int pi = idx % 33;
  int bc = idx / 33;
  float2* base = vc + (size_t)bc * NMODE;
  if (pi == 0) {
    base[0].y = 0.f;
  } else if (pi == 32) {
    base[32 * KY].x *= 0.5f;
    base[32 * KY].y *= 0.5f;
  } else {
    int ua = pi, ub = 64 - pi;
    float2 a = base[ua * KY], b2 = base[ub * KY];
    base[ua * KY] = make_float2(0.5f * (a.x + b2.x), 0.5f * (a.y - b2.y));
    base[ub * KY] = make_float2(0.5f * (b2.x + a.x), 0.5f * (b2.y - a.y));
  }
}

// ---------------- K4: pw1 in spectral space (float2 io), XCD-pinned per batch ----------------
__global__ __launch_bounds__(256) void k_pw1(const float2* __restrict__ xc,
                                             const float* __restrict__ pw1,
                                             float2* __restrict__ hc) {
  __shared__ float wT[CH][CH + 1];
  int bid = blockIdx.x;
  int b = ((bid & 7) << 1) | ((bid >> 8) & 1);
  int jt = (bid >> 3) & 31;
  int t = threadIdx.x;
  for (int e = t; e < CH * CH; e += 256) {
    int p = e >> 7, c = e & 127;
    wT[c][p] = pw1[e];
  }
  __syncthreads();
  int tx = t & 15, ty = t >> 4;
  int j0 = jt * 64 + tx * 4;
  float accR[4][8] = {}, accI[4][8] = {};
  for (int c = 0; c < CH; ++c) {
    const float4* x4 = (const float4*)&xc[((size_t)b * CH + c) * NMODE + j0];
    float4 v0 = x4[0], v1 = x4[1];
    float xrv[4] = {v0.x, v0.z, v1.x, v1.z};
    float xiv[4] = {v0.y, v0.w, v1.y, v1.w};
    float w[8];
    #pragma unroll
    for (int pp = 0; pp < 8; ++pp) w[pp] = wT[c][ty * 8 + pp];
    #pragma unroll
    for (int jj = 0; jj < 4; ++jj)
      #pragma unroll
      for (int pp = 0; pp < 8; ++pp) {
        accR[jj][pp] += w[pp] * xrv[jj];
        accI[jj][pp] += w[pp] * xiv[jj];
      }
  }
  #pragma unroll
  for (int pp = 0; pp < 8; ++pp) {
    int p = ty * 8 + pp;
    float4* o4 = (float4*)&hc[((size_t)b * CH + p) * NMODE + j0];
    o4[0] = make_float4(accR[0][pp], accI[0][pp], accR[1][pp], accI[1][pp]);
    o4[1] = make_float4(accR[2][pp], accI[2][pp], accR[3][pp], accI[3][pp]);
  }
}

// ---------------- K5: fused iDFT + bias + gelu + pw2, parity + async dbuf + E-tile ----------------
// grid = 4096: b = (bid&7)|(((bid>>3)&1)<<3) (XCD-pinned b), pg = (bid>>4)&31, xs = bid>>9.
__global__ __launch_bounds__(256) void k_idft_partial(const float2* __restrict__ hc,
                                                      const float* __restrict__ pb1,
                                                      const float* __restrict__ pw2,
                                                      float* __restrict__ partial) {
  __shared__ float2 tw[DIM];                  // 1 KB
  __shared__ float2 hfs[2][NMODE];            // 32 KB dbuf
  __shared__ float2 sbuf[16][KY];             // [x-slot][ky] 4 KB
  __shared__ float4 sE[8][32];                // E-tile 4 KB
  int bid = blockIdx.x;
  int b = (bid & 7) | (((bid >> 3) & 1) << 3);
  int pg = (bid >> 4) & 31, xs = bid >> 9;
  int x0 = xs * 8;
  int t = threadIdx.x;
  int wv = t >> 6, lane = t & 63;
  if (t < 128) {
    float ang = (float)(2.0 * M_PI) * (float)t / 128.0f;
    tw[t] = make_float2(cosf(ang), sinf(ang));
  }

  #define STAGE_H(bf, pp_)                                                           \
    {                                                                                \
      const char* srcb = (const char*)(hc + ((size_t)b * CH + pg * PPG + (pp_)) * NMODE); \
      _Pragma("unroll")                                                              \
      for (int n = 0; n < 4; ++n) {                                                  \
        int nu = wv * 4 + n;                                                         \
        async16(srcb + (size_t)nu * 1024 + lane * 16,                                \
                (char*)&hfs[bf][0] + (size_t)nu * 1024 + lane * 16);                 \
      }                                                                              \
    }

  STAGE_H(0, 0);
  __syncthreads();                            // tw + hfs[0] ready
  {
    int xq = t >> 5, j = t & 31;
    int x = x0 + xq;
    int kxE = (j < 16) ? (2 * j) : (2 * j + 64);
    float2 wE = tw[(kxE * x) & 127];
    float2 wO = tw[((kxE + 1) * x) & 127];
    sE[xq][j] = make_float4(wE.x, wE.y, wO.x, wO.y);
  }
  int y = t & 63, xh = t >> 6;
  float Cr[KY], Sr[KY];
  #pragma unroll
  for (int ky = 0; ky < KY; ++ky) {
    float2 w = tw[(ky * y) & 127];
    float wk = (ky == 0) ? 1.f : 2.f;
    Cr[ky] = wk * w.x;
    Sr[ky] = -wk * w.y;
  }
  __syncthreads();                            // sE visible to all
  int xqA = t >> 5, kyA = t & 31;
  float res[8] = {0.f, 0.f, 0.f, 0.f, 0.f, 0.f, 0.f, 0.f};
  for (int pp = 0; pp < PPG; ++pp) {
    int p = pg * PPG + pp;
    int cur = pp & 1;
    if (pp) __syncthreads();                  // hfs[cur] staged; sbuf free
    if (pp + 1 < PPG) STAGE_H(cur ^ 1, pp + 1);
    // phase A with u-parity via E-tile: s[x]=Pe+Po, s[x+64]=Pe-Po
    {
      float per = 0.f, pei = 0.f, por = 0.f, poi = 0.f;
      #pragma unroll
      for (int j = 0; j < 32; ++j) {
        float4 E = sE[xqA][j];
        float2 h0 = hfs[cur][(2 * j) * KY + kyA];
        float2 h1 = hfs[cur][(2 * j + 1) * KY + kyA];
        per += h0.x * E.x - h0.y * E.y;
        pei += h0.x * E.y + h0.y * E.x;
        por += h1.x * E.z - h1.y * E.w;
        poi += h1.x * E.w + h1.y * E.z;
      }
      sbuf[xqA][kyA]     = make_float2(per + por, pei + poi);
      sbuf[xqA + 8][kyA] = make_float2(per - por, pei - poi);
    }
    __syncthreads();
    // phase B with ky-parity: out[y] = Ae+Ao, out[y+64] = Ae-Ao (float4 sbuf reads)
    float pb = pb1[p], pw = pw2[p];
    #pragma unroll
    for (int sl = 0; sl < 4; ++sl) {
      int s_i = xh + sl * 4;
      float ae = 0.f, ao = 0.f;
      #pragma unroll
      for (int ky = 0; ky < KY; ky += 2) {
        float4 v = *(const float4*)&sbuf[s_i][ky];   // {re_ky, im_ky, re_ky1, im_ky1}
        ae += v.x * Cr[ky] + v.y * Sr[ky];
        ao += v.z * Cr[ky + 1] + v.w * Sr[ky + 1];
      }
      float hlo = (ae + ao) * (1.f / 16384.f) + pb;
      float hhi = (ae - ao) * (1.f / 16384.f) + pb;
      float zlo = 1.5957691216057308f * (hlo + 0.044715f * hlo * hlo * hlo);
      float zhi = 1.5957691216057308f * (hhi + 0.044715f * hhi * hhi * hhi);
      res[sl * 2]     += pw * hlo * __builtin_amdgcn_rcpf(1.f + __expf(-zlo));
      res[sl * 2 + 1] += pw * hhi * __builtin_amdgcn_rcpf(1.f + __expf(-zhi));
    }
  }
  #undef STAGE_H
  size_t pbase = ((size_t)pg * B + b) * N2;
  #pragma unroll
  for (int sl = 0; sl < 4; ++sl) {
    int s_i = xh + sl * 4;
    int x = x0 + (s_i & 7) + ((s_i >> 3) << 6);
    partial[pbase + x * DIM + y]      = res[sl * 2];
    partial[pbase + x * DIM + y + 64] = res[sl * 2 + 1];
  }
}

// ---------------- K6: reduce p-group partials + pb2 ----------------
__global__ __launch_bounds__(256) void k_reduce(const float* __restrict__ partial,
                                                const float* __restrict__ pb2,
                                                float* __restrict__ outp) {
  int idx = blockIdx.x * 256 + threadIdx.x;
  if (idx >= B * N2) return;
  float s = pb2[0];
  #pragma unroll
  for (int pg = 0; pg < PG; ++pg) s += partial[(size_t)pg * B * N2 + idx];
  outp[idx] = s;
}

extern "C" void kernel_launch(void* const* d_in, const int* in_sizes, int n_in,
                              void* d_out, int out_size, void* d_ws, size_t ws_size,
                              hipStream_t stream) {
  const float* z   = (const float*)d_in[0];
  const float* lw  = (const float*)d_in[1];
  const float* lb  = (const float*)d_in[2];
  const float* wr1 = (const float*)d_in[3];
  const float* wi1 = (const float*)d_in[4];
  const float* wr2 = (const float*)d_in[5];
  const float* wi2 = (const float*)d_in[6];
  const float* pw1 = (const float*)d_in[7];
  const float* pb1 = (const float*)d_in[8];
  const float* pw2 = (const float*)d_in[9];
  const float* pb2 = (const float*)d_in[10];
  float* out = (float*)d_out;
  float* ws = (float*)d_ws;

  float* zfr = ws;
  float* zfi = zfr + 32768;
  float2* Ac = (float2*)(ws + 65536);
  float2* Bc = Ac + (size_t)B * CH * NMODE;
  float2* t1 = Bc;   // aliases Bc (dead until first k_spec write)

  k_zf1<<<B * 8, 256, 0, stream>>>(z, t1);
  k_zf2<<<B * 2, 256, 0, stream>>>(t1, zfr, zfi);
  k_lift<<<(B * CH * NMODE) / 256, 256, 0, stream>>>(zfr, zfi, lw, lb, Ac);

  const size_t WSTRIDE = (size_t)CH * CH * MODES * MODES;
  float2 *ir = Ac, *oc = Bc;
  for (int l = 0; l < NLAYERS; ++l) {
    k_spec<<<512, 256, 0, stream>>>(ir,
                                    wr1 + l * WSTRIDE, wi1 + l * WSTRIDE,
                                    wr2 + l * WSTRIDE, wi2 + l * WSTRIDE,
                                    oc);
    if (l < NLAYERS - 1)
      k_proj0<<<(B * CH * 33 + 255) / 256, 256, 0, stream>>>(oc);
    float2* tmp = ir; ir = oc; oc = tmp;
  }
  k_pw1<<<512, 256, 0, stream>>>(ir, pw1, oc);
  float* partial = (float*)ir;   // aliases Ac (33.5 MB < 67 MB, dead after k_pw1)
  k_idft_partial<<<B * PG * 8, 256, 0, stream>>>(oc, pb1, pw2, partial);
  k_reduce<<<(B * N2) / 256, 256, 0, stream>>>(partial, pb2, out);
}